// Round 1
// baseline (1011.596 us; speedup 1.0000x reference)
//
#include <hip/hip_runtime.h>

// VectorQuantizer: latents (16,128,64,64) f32, codebook (1024,128) f32.
// out[b,d,h,w] = codebook[argmin_k ((x2 - 2*dot(x,e_k)) + e2_k)][d]
// Numerics replicate np: d2 = (x2 - 2*dot) + e2, two fp32 roundings, argmin
// with first-index-wins ties.

#define VQ_D 128
#define VQ_K 1024
#define VQ_HW 4096   // 64*64
#define VQ_NPIX 65536

__global__ __launch_bounds__(128, 2)
void vq_e2_kernel(const float* __restrict__ cb, float* __restrict__ e2) {
    int k = blockIdx.x * blockDim.x + threadIdx.x;
    if (k < VQ_K) {
        float s = 0.f;
        #pragma unroll
        for (int d = 0; d < VQ_D; ++d) {
            float v = cb[k * VQ_D + d];
            s = fmaf(v, v, s);
        }
        e2[k] = s;
    }
}

__global__ __launch_bounds__(128, 2)
void vq_main_kernel(const float* __restrict__ latents,
                    const float* __restrict__ cb,
                    const float* __restrict__ e2,
                    float* __restrict__ out) {
    const int lane = threadIdx.x & 63;
    const int wave = threadIdx.x >> 6;          // 0 or 1: splits K range
    const int gp   = blockIdx.x * 64 + lane;    // global pixel id
    const int b    = gp >> 12;                  // 4096 pixels per batch image
    const int hw   = gp & 4095;

    const float* xbase = latents + (size_t)b * VQ_D * VQ_HW + hw;

    // x[d] for this pixel: strided by HW, coalesced across lanes.
    float x[VQ_D];
    #pragma unroll
    for (int d = 0; d < VQ_D; ++d) x[d] = xbase[(size_t)d * VQ_HW];

    // x2: any fp32 summation works — discrepancies vs np are grid-multiple
    // shifts of d2 that cannot change the argmin ordering.
    float x2 = 0.f;
    #pragma unroll
    for (int d = 0; d < VQ_D; ++d) x2 = fmaf(x[d], x[d], x2);

    float best = 1e30f;
    int   bi   = 0;

    const int kbeg = wave * (VQ_K / 2);
    const int kend = kbeg + (VQ_K / 2);

    // 8 codes in flight; codebook indices are wave-uniform -> scalar loads.
    #pragma unroll 1
    for (int k0 = kbeg; k0 < kend; k0 += 8) {
        float dot[8];
        #pragma unroll
        for (int j = 0; j < 8; ++j) dot[j] = 0.f;

        #pragma unroll
        for (int d = 0; d < VQ_D; ++d) {
            #pragma unroll
            for (int j = 0; j < 8; ++j) {
                dot[j] = fmaf(x[d], cb[(k0 + j) * VQ_D + d], dot[j]);
            }
        }

        #pragma unroll
        for (int j = 0; j < 8; ++j) {
            // Replicate np's rounding: t2 = fl(x2 - 2*dot) (2*dot exact),
            // t3 = fl(t2 + e2). Strict < with ascending k = first-index ties.
            float t2 = x2 - 2.0f * dot[j];
            float t3 = t2 + e2[k0 + j];
            if (t3 < best) { best = t3; bi = k0 + j; }
        }
    }

    // Merge the two waves' K-halves. Wave 1's indices are all larger, so it
    // only wins on strictly smaller value (first-index tie-break preserved).
    __shared__ float sval[64];
    __shared__ int   sidx[64];
    __shared__ int   widx[64];

    if (wave == 1) { sval[lane] = best; sidx[lane] = bi; }
    __syncthreads();
    if (wave == 0) {
        if (sval[lane] < best) { best = sval[lane]; bi = sidx[lane]; }
        widx[lane] = bi;
    }
    __syncthreads();

    const int fi = widx[lane];
    const float* crow  = cb + (size_t)fi * VQ_D;
    float*       obase = out + (size_t)b * VQ_D * VQ_HW + hw;

    // Both waves split the 128 channels of the writeback.
    #pragma unroll
    for (int d = 0; d < 64; ++d) {
        const int dd = d + wave * 64;
        obase[(size_t)dd * VQ_HW] = crow[dd];
    }
}

extern "C" void kernel_launch(void* const* d_in, const int* in_sizes, int n_in,
                              void* d_out, int out_size, void* d_ws, size_t ws_size,
                              hipStream_t stream) {
    const float* latents = (const float*)d_in[0];
    const float* cb      = (const float*)d_in[1];
    float*       e2      = (float*)d_ws;      // 1024 floats of scratch
    float*       out     = (float*)d_out;

    vq_e2_kernel<<<dim3(VQ_K / 128), dim3(128), 0, stream>>>(cb, e2);
    vq_main_kernel<<<dim3(VQ_NPIX / 64), dim3(128), 0, stream>>>(latents, cb, e2, out);
}